// Round 11
// baseline (81.664 us; speedup 1.0000x reference)
//
#include <hip/hip_runtime.h>
#include <math.h>

// Problem constants
#define H_   768
#define NH_  12
#define DH_  64
#define NL_  50
#define NC_  16
#define S_   8192
#define NLH_ 640     // padded (h,l) columns (600 used)
#define MT_  128     // m-tiles of 64 s-rows
#define NT3_ 10      // n-tiles of 64 cols
#define KC_  8       // split-K chunks for prep1 tiles

typedef __attribute__((ext_vector_type(8))) short short8;
typedef __attribute__((ext_vector_type(4))) short short4v;
typedef __attribute__((ext_vector_type(4))) float f32x4;
typedef unsigned short u16;

#define AS1(p) ((const __attribute__((address_space(1))) void*)(p))
#define AS3(p) ((__attribute__((address_space(3))) void*)(p))

__device__ inline u16 f2b(float f) {
    union { float f; unsigned u; } x; x.f = f;
    return (u16)((x.u + 0x7FFFu + ((x.u >> 16) & 1u)) >> 16);
}
__device__ inline short8 cvt8(const float* __restrict__ src) {
    const float4 v0 = *reinterpret_cast<const float4*>(src);
    const float4 v1 = *reinterpret_cast<const float4*>(src + 4);
    short8 o;
    o[0] = f2b(v0.x); o[1] = f2b(v0.y); o[2] = f2b(v0.z); o[3] = f2b(v0.w);
    o[4] = f2b(v1.x); o[5] = f2b(v1.y); o[6] = f2b(v1.z); o[7] = f2b(v1.w);
    return o;
}

// ---------------------------------------------------------------------------
// prep1 (one launch):
//   blocks 0..95   : SPLIT-K MFMA partial tiles for qf (mat 0) / M2 (mat 1)
//   blocks 96..3167: enc fp32 -> bf16 (linear, BW-bound)
// ---------------------------------------------------------------------------
#define PB_TILE 96

__global__ __launch_bounds__(256)
void prep1(const float* __restrict__ enc, const float* __restrict__ lq,
           const float* __restrict__ lwt, const float* __restrict__ ipw,
           const float* __restrict__ ow,
           u16* __restrict__ enc_b, float* __restrict__ pbuf)
{
    __shared__ u16 As[64 * 32];    // 4 KB
    __shared__ u16 Bs[128 * 32];   // 8 KB

    const int b = blockIdx.x, tid = threadIdx.x;

    if (b >= PB_TILE) {
        const long i8 = (long)(b - PB_TILE) * 2048 + (long)tid * 8;
        *reinterpret_cast<short8*>(enc_b + i8) = cvt8(enc + i8);
        return;
    }

    const int mat = b / 48, r2 = b % 48, kc = r2 / 6, jt = r2 % 6;
    const long n0 = (long)jt * 128;
    const bool isM2 = (mat == 1);
    const int lane = tid & 63, w = tid >> 6;
    const int rr = lane & 15, g = lane >> 4;

    f32x4 acc[4][2];
    #pragma unroll
    for (int m = 0; m < 4; ++m)
        #pragma unroll
        for (int n = 0; n < 2; ++n)
            #pragma unroll
            for (int j = 0; j < 4; ++j) acc[m][n][j] = 0.f;

    const float* Asrc = isM2 ? lwt : lq;

    #pragma unroll
    for (int ki = 0; ki < 3; ++ki) {
        const int k0 = kc * 96 + ki * 32;
        {
            const int row = tid >> 2, sp = tid & 3;
            short8 o;
            #pragma unroll
            for (int i = 0; i < 8; ++i) o[i] = 0;
            if (row < NL_) o = cvt8(Asrc + (long)row * H_ + k0 + sp * 8);
            const int ss = sp ^ ((row >> 1) & 3);
            *reinterpret_cast<short8*>(As + row * 32 + ss * 8) = o;
        }
        if (!isM2) {
            #pragma unroll
            for (int it = 0; it < 2; ++it) {
                const int gid = it * 256 + tid;
                const int row = gid >> 2, sp = gid & 3;
                const short8 o = cvt8(ipw + (n0 + row) * H_ + k0 + sp * 8);
                const int ss = sp ^ ((row >> 1) & 3);
                *reinterpret_cast<short8*>(Bs + row * 32 + ss * 8) = o;
            }
        } else {
            #pragma unroll
            for (int it = 0; it < 4; ++it) {
                const int gid = it * 256 + tid;       // kq*128 + n
                const int n = gid & 127, kq = gid >> 7;
                short4v o4;
                #pragma unroll
                for (int i = 0; i < 4; ++i)
                    o4[i] = f2b(ow[(long)(k0 + kq * 4 + i) * H_ + n0 + n]);
                const int byte = n * 64 + (((kq >> 1) ^ ((n >> 1) & 3)) << 4) + (kq & 1) * 8;
                *reinterpret_cast<short4v*>((char*)Bs + byte) = o4;
            }
        }
        __syncthreads();

        short8 a[4], bb[2];
        #pragma unroll
        for (int m = 0; m < 4; ++m) {
            const int row = m * 16 + rr;
            a[m] = *reinterpret_cast<const short8*>(As + row * 32 + ((g ^ ((row >> 1) & 3)) * 8));
        }
        #pragma unroll
        for (int n = 0; n < 2; ++n) {
            const int nr = w * 32 + n * 16 + rr;
            bb[n] = *reinterpret_cast<const short8*>(Bs + nr * 32 + ((g ^ ((nr >> 1) & 3)) * 8));
        }
        #pragma unroll
        for (int m = 0; m < 4; ++m)
            #pragma unroll
            for (int n = 0; n < 2; ++n)
                acc[m][n] = __builtin_amdgcn_mfma_f32_16x16x32_bf16(a[m], bb[n], acc[m][n], 0, 0, 0);
        __syncthreads();
    }

    float* P = pbuf + (long)(mat * KC_ + kc) * 64 * H_;
    #pragma unroll
    for (int m = 0; m < 4; ++m)
        #pragma unroll
        for (int n = 0; n < 2; ++n) {
            const long col = n0 + w * 32 + n * 16 + rr;
            #pragma unroll
            for (int j = 0; j < 4; ++j) {
                const int row = m * 16 + g * 4 + j;
                P[(long)row * H_ + col] = acc[m][n][j];
            }
        }
}

// ---------------------------------------------------------------------------
// prep2 (one launch):
//   blocks 0..143 : (mat, h, jt): qk/W2 = A_h @ wk_h/wv_h  MFMA, K=64 one-shot
//   blocks 144..193 : constL[l]
//   block 194 : zero pad rows 600..639 of qkL, W2L
// ---------------------------------------------------------------------------
__global__ __launch_bounds__(256)
void prep2(const float* __restrict__ pbuf, const float* __restrict__ ipw,
           const float* __restrict__ ipb, const float* __restrict__ lwt,
           const float* __restrict__ ob,
           u16* __restrict__ qkL, u16* __restrict__ W2L, float* __restrict__ constL)
{
    __shared__ u16 As2[64 * 64];    // 8 KB
    __shared__ u16 Bs2[128 * 64];   // 16 KB

    const int b = blockIdx.x, tid = threadIdx.x;

    if (b < 144) {
        const int mat = b / 72, r2 = b % 72, h = r2 / 6, jt = r2 % 6;
        const long n0 = (long)jt * 128;
        const int kb = H_ + mat * H_ + h * DH_;      // ipw row base (wk / wv)
        const int lane = tid & 63, w = tid >> 6;
        const int rr = lane & 15, g = lane >> 4;

        #pragma unroll
        for (int it = 0; it < 2; ++it) {
            const int gid = it * 256 + tid;          // row*8 + sp
            const int row = gid >> 3, sp = gid & 7;
            float a8[8];
            #pragma unroll
            for (int i = 0; i < 8; ++i) a8[i] = 0.f;
            #pragma unroll
            for (int kc = 0; kc < KC_; ++kc) {
                const float* p = pbuf + ((long)(mat * KC_ + kc) * 64 + row) * H_
                               + h * DH_ + sp * 8;
                const float4 v0 = *reinterpret_cast<const float4*>(p);
                const float4 v1 = *reinterpret_cast<const float4*>(p + 4);
                a8[0] += v0.x; a8[1] += v0.y; a8[2] += v0.z; a8[3] += v0.w;
                a8[4] += v1.x; a8[5] += v1.y; a8[6] += v1.z; a8[7] += v1.w;
            }
            short8 o;
            if (mat == 0) {
                #pragma unroll
                for (int i = 0; i < 8; ++i)
                    o[i] = f2b((row < NL_) ? 0.125f * (a8[i] + ipb[h * DH_ + sp * 8 + i]) : 0.f);
            } else {
                #pragma unroll
                for (int i = 0; i < 8; ++i) o[i] = f2b(a8[i]);
            }
            *reinterpret_cast<short8*>(As2 + row * 64 + ((sp ^ (row & 7)) * 8)) = o;
        }
        #pragma unroll
        for (int it = 0; it < 8; ++it) {
            const int gid = it * 256 + tid;          // kq*128 + n, kq 0..15
            const int n = gid & 127, kq = gid >> 7;
            short4v o4;
            #pragma unroll
            for (int i = 0; i < 4; ++i)
                o4[i] = f2b(ipw[(long)(kb + kq * 4 + i) * H_ + n0 + n]);
            const int byte = n * 128 + (((kq >> 1) ^ (n & 7)) << 4) + (kq & 1) * 8;
            *reinterpret_cast<short4v*>((char*)Bs2 + byte) = o4;
        }
        __syncthreads();

        f32x4 acc[4][2];
        #pragma unroll
        for (int m = 0; m < 4; ++m)
            #pragma unroll
            for (int n = 0; n < 2; ++n)
                #pragma unroll
                for (int j = 0; j < 4; ++j) acc[m][n][j] = 0.f;

        #pragma unroll
        for (int ks = 0; ks < 2; ++ks) {
            short8 a[4], bb[2];
            #pragma unroll
            for (int m = 0; m < 4; ++m) {
                const int row = m * 16 + rr, s = ks * 4 + g;
                a[m] = *reinterpret_cast<const short8*>(As2 + row * 64 + ((s ^ (row & 7)) * 8));
            }
            #pragma unroll
            for (int n = 0; n < 2; ++n) {
                const int nr = w * 32 + n * 16 + rr, s = ks * 4 + g;
                bb[n] = *reinterpret_cast<const short8*>(Bs2 + nr * 64 + ((s ^ (nr & 7)) * 8));
            }
            #pragma unroll
            for (int m = 0; m < 4; ++m)
                #pragma unroll
                for (int n = 0; n < 2; ++n)
                    acc[m][n] = __builtin_amdgcn_mfma_f32_16x16x32_bf16(a[m], bb[n], acc[m][n], 0, 0, 0);
        }

        u16* O = mat ? W2L : qkL;
        #pragma unroll
        for (int m = 0; m < 4; ++m)
            #pragma unroll
            for (int n = 0; n < 2; ++n) {
                const long col = n0 + w * 32 + n * 16 + rr;
                #pragma unroll
                for (int j = 0; j < 4; ++j) {
                    const int l = m * 16 + g * 4 + j;
                    if (l < NL_)
                        O[(long)(h * NL_ + l) * H_ + col] = f2b(acc[m][n][j]);
                }
            }
        return;
    }

    if (b < 194) {   // constL[l]
        const int l = b - 144;
        __shared__ float r4[4];
        const int lane = tid & 63, w = tid >> 6;
        float s = 0.f;
        #pragma unroll
        for (int r = 0; r < 3; ++r) {
            const int i = tid + 256 * r;
            float m2v = 0.f;
            #pragma unroll
            for (int kc = 0; kc < KC_; ++kc)
                m2v += pbuf[((long)(KC_ + kc) * 64 + l) * H_ + i];
            s += m2v * ipb[2 * H_ + i] + lwt[(long)l * H_ + i] * ob[i];
        }
        #pragma unroll
        for (int o2 = 1; o2 < 64; o2 <<= 1) s += __shfl_xor(s, o2);
        if (lane == 0) r4[w] = s;
        __syncthreads();
        if (tid == 0) constL[l] = r4[0] + r4[1] + r4[2] + r4[3];
        return;
    }

    {
        short8 z;
        #pragma unroll
        for (int i = 0; i < 8; ++i) z[i] = 0;
        for (int i = tid; i < 40 * H_ / 8; i += 256) {
            *reinterpret_cast<short8*>(qkL + (long)600 * H_ + i * 8) = z;
            *reinterpret_cast<short8*>(W2L + (long)600 * H_ + i * 8) = z;
        }
    }
}

// ---------------------------------------------------------------------------
// fused_gemm: WAVE-AUTONOMOUS, barrier-free. Block = ONE wave (64 threads)
// owning a 64-row x 64-col tile of BOTH logits (qk) and Z (W2). Wave-private
// double-buffered LDS filled by global_load_lds; per-wave vmcnt(0) is the
// only synchronization. Softmax partials computed fully in-wave (shfl).
// Grid 1280 = 128 m-tiles x 10 n-tiles, XCD-bijective (1280 = 8*160).
// ---------------------------------------------------------------------------
__global__ __launch_bounds__(64)
void fused_gemm(const u16* __restrict__ enc_b, const u16* __restrict__ qkL,
                const u16* __restrict__ W2L,
                float* __restrict__ pmg, float* __restrict__ ppg,
                float* __restrict__ pzg)
{
    const int flat = blockIdx.x;                        // 0..1279
    const int wg   = (flat & 7) * 160 + (flat >> 3);    // XCD-bijective
    const int mt   = wg / NT3_, ntb = wg % NT3_;
    const long m0 = (long)mt * 64, n0 = (long)ntb * 64;

    __shared__ u16 Abuf[2][2048];   // 64 rows x 32 k
    __shared__ u16 Qbuf[2][2048];   // 64 cols x 32 k
    __shared__ u16 Zbuf[2][2048];

    const int lane = threadIdx.x;
    const int rr = lane & 15, g = lane >> 4;

    f32x4 accq[4][4], accz[4][4];
    #pragma unroll
    for (int m = 0; m < 4; ++m)
        #pragma unroll
        for (int n = 0; n < 4; ++n)
            #pragma unroll
            for (int j = 0; j < 4; ++j) { accq[m][n][j] = 0.f; accz[m][n][j] = 0.f; }

    auto stage = [&](int t, int buf) {
        const int k0 = t * 32;
        #pragma unroll
        for (int i = 0; i < 4; ++i) {
            const int gr = i * 64 + lane;
            const int row = gr >> 2, sp = gr & 3;
            const int ss = sp ^ ((row >> 1) & 3);
            __builtin_amdgcn_global_load_lds(AS1(enc_b + (m0 + row) * H_ + k0 + ss * 8),
                                             AS3(Abuf[buf] + gr * 8), 16, 0, 0);
            __builtin_amdgcn_global_load_lds(AS1(qkL + (n0 + row) * H_ + k0 + ss * 8),
                                             AS3(Qbuf[buf] + gr * 8), 16, 0, 0);
            __builtin_amdgcn_global_load_lds(AS1(W2L + (n0 + row) * H_ + k0 + ss * 8),
                                             AS3(Zbuf[buf] + gr * 8), 16, 0, 0);
        }
    };

    stage(0, 0);

    for (int t = 0; t < 24; ++t) {
        // own loads for tile t have landed; no cross-wave sync needed
        asm volatile("s_waitcnt vmcnt(0)" ::: "memory");
        __builtin_amdgcn_sched_barrier(0);
        if (t + 1 < 24) stage(t + 1, (t + 1) & 1);   // overlap next-tile loads

        const int cb = t & 1;
        short8 a[4], bq[4], bz[4];
        #pragma unroll
        for (int m = 0; m < 4; ++m) {
            const int row = m * 16 + rr;
            a[m] = *reinterpret_cast<const short8*>(
                Abuf[cb] + row * 32 + ((g ^ ((row >> 1) & 3)) * 8));
        }
        #pragma unroll
        for (int n = 0; n < 4; ++n) {
            const int col = n * 16 + rr;
            const int so = (g ^ ((col >> 1) & 3)) * 8;
            bq[n] = *reinterpret_cast<const short8*>(Qbuf[cb] + col * 32 + so);
            bz[n] = *reinterpret_cast<const short8*>(Zbuf[cb] + col * 32 + so);
        }
        #pragma unroll
        for (int m = 0; m < 4; ++m)
            #pragma unroll
            for (int n = 0; n < 4; ++n) {
                accq[m][n] = __builtin_amdgcn_mfma_f32_16x16x32_bf16(a[m], bq[n], accq[m][n], 0, 0, 0);
                accz[m][n] = __builtin_amdgcn_mfma_f32_16x16x32_bf16(a[m], bz[n], accz[m][n], 0, 0, 0);
            }
    }

    // ---- in-wave softmax partials over the tile's 64 rows ----
    // acc element (m,n,j): row = m*16 + g*4 + j, col = n*16 + rr
    #pragma unroll
    for (int n = 0; n < 4; ++n) {
        float mx = -INFINITY;
        #pragma unroll
        for (int m = 0; m < 4; ++m)
            #pragma unroll
            for (int j = 0; j < 4; ++j) mx = fmaxf(mx, accq[m][n][j]);
        mx = fmaxf(mx, __shfl_xor(mx, 16));
        mx = fmaxf(mx, __shfl_xor(mx, 32));
        float s = 0.f, z = 0.f;
        #pragma unroll
        for (int m = 0; m < 4; ++m)
            #pragma unroll
            for (int j = 0; j < 4; ++j) {
                const float e = __expf(accq[m][n][j] - mx);
                s += e;
                z += e * accz[m][n][j];
            }
        s += __shfl_xor(s, 16); s += __shfl_xor(s, 32);
        z += __shfl_xor(z, 16); z += __shfl_xor(z, 32);
        if (g == 0) {
            const long o = (long)mt * NLH_ + n0 + n * 16 + rr;
            pmg[o] = mx; ppg[o] = s; pzg[o] = z;
        }
    }
}

// ---------------------------------------------------------------------------
// combine: block = label l, 64 threads. LDS-preload all 128x12 partials,
// 12 threads run the serial flash-prefix from LDS; emit every 8th m-tile.
// ---------------------------------------------------------------------------
__global__ __launch_bounds__(64)
void combine(const float* __restrict__ pmg, const float* __restrict__ ppg,
             const float* __restrict__ pzg, const float* __restrict__ constL,
             float* __restrict__ out)
{
    const int l = blockIdx.x, t = threadIdx.x;
    __shared__ float sm[MT_][12], sp_[MT_][12], sz[MT_][12];
    __shared__ float sc[16][12];

    #pragma unroll
    for (int r = 0; r < 2; ++r) {
        const int m = t + r * 64;
        #pragma unroll
        for (int h = 0; h < NH_; ++h) {
            const long o = (long)m * NLH_ + h * NL_ + l;
            sm[m][h]  = pmg[o];
            sp_[m][h] = ppg[o];
            sz[m][h]  = pzg[o];
        }
    }
    __syncthreads();

    if (t < NH_) {
        float M = -INFINITY, S = 0.f, A = 0.f;
        for (int mt = 0; mt < MT_; ++mt) {
            const float mc = sm[mt][t], pc = sp_[mt][t], zc = sz[mt][t];
            const float Mn = fmaxf(M, mc);
            const float ea = __expf(M - Mn), eb = __expf(mc - Mn);
            S = S * ea + pc * eb;
            A = A * ea + zc * eb;
            M = Mn;
            if ((mt & 7) == 7) sc[mt >> 3][t] = A / S;
        }
    }
    __syncthreads();
    if (t < NC_) {
        float s = constL[l];
        #pragma unroll
        for (int h = 0; h < NH_; ++h) s += sc[t][h];
        out[(long)t * NL_ + l] = s;
    }
}

// ---------------------------------------------------------------------------
extern "C" void kernel_launch(void* const* d_in, const int* in_sizes, int n_in,
                              void* d_out, int out_size, void* d_ws, size_t ws_size,
                              hipStream_t stream) {
    const float* enc = (const float*)d_in[0];
    const float* lq  = (const float*)d_in[1];
    const float* lwt = (const float*)d_in[2];   // flat == lw (50, 768)
    const float* ipw = (const float*)d_in[3];
    const float* ipb = (const float*)d_in[4];
    const float* ow  = (const float*)d_in[5];
    const float* ob  = (const float*)d_in[6];
    float* out = (float*)d_out;

    // workspace
    float* wsf    = (float*)d_ws;
    float* pbuf   = wsf;                          // 2*8*64*768 = 786432
    float* constL = pbuf + (long)2 * KC_ * 64 * H_;  // 64
    float* pmg    = constL + 64;                  // 128*640
    float* ppg    = pmg + (long)MT_ * NLH_;
    float* pzg    = ppg + (long)MT_ * NLH_;
    u16* enc_b = (u16*)(pzg + (long)MT_ * NLH_);  // 8192*768
    u16* qkL   = enc_b + (long)S_ * H_;           // 640*768
    u16* W2L   = qkL + (long)NLH_ * H_;           // 640*768

    prep1<<<dim3(PB_TILE + 3072), 256, 0, stream>>>(
        enc, lq, lwt, ipw, ow, enc_b, pbuf);

    prep2<<<dim3(195), 256, 0, stream>>>(pbuf, ipw, ipb, lwt, ob,
                                         qkL, W2L, constL);

    fused_gemm<<<dim3(MT_ * NT3_), 64, 0, stream>>>(enc_b, qkL, W2L, pmg, ppg, pzg);

    combine<<<dim3(NL_), 64, 0, stream>>>(pmg, ppg, pzg, constL, out);
}

// Round 12
// 55.821 us; speedup vs baseline: 1.4630x; 1.4630x over previous
//
#include <hip/hip_runtime.h>
#include <math.h>

// Problem constants
#define H_   768
#define NH_  12
#define DH_  64
#define NL_  50
#define NC_  16
#define S_   8192
#define NLH_ 640     // padded (h,l) columns (600 used)
#define MT_  64      // m-tiles of 128 s-rows
#define NT3_ 10      // n-tiles of 64 cols
#define KC_  8       // split-K chunks for prep1 tiles

typedef __attribute__((ext_vector_type(8))) short short8;
typedef __attribute__((ext_vector_type(4))) short short4v;
typedef __attribute__((ext_vector_type(4))) float f32x4;
typedef unsigned short u16;

#define AS1(p) ((const __attribute__((address_space(1))) void*)(p))
#define AS3(p) ((__attribute__((address_space(3))) void*)(p))

__device__ inline u16 f2b(float f) {
    union { float f; unsigned u; } x; x.f = f;
    return (u16)((x.u + 0x7FFFu + ((x.u >> 16) & 1u)) >> 16);
}
__device__ inline short8 cvt8(const float* __restrict__ src) {
    const float4 v0 = *reinterpret_cast<const float4*>(src);
    const float4 v1 = *reinterpret_cast<const float4*>(src + 4);
    short8 o;
    o[0] = f2b(v0.x); o[1] = f2b(v0.y); o[2] = f2b(v0.z); o[3] = f2b(v0.w);
    o[4] = f2b(v1.x); o[5] = f2b(v1.y); o[6] = f2b(v1.z); o[7] = f2b(v1.w);
    return o;
}

// ---------------------------------------------------------------------------
// prep1 (one launch):
//   blocks 0..95   : SPLIT-K MFMA partial tiles for qf (mat 0) / M2 (mat 1)
//   blocks 96..3167: enc fp32 -> bf16 (linear, BW-bound)
// ---------------------------------------------------------------------------
#define PB_TILE 96

__global__ __launch_bounds__(256)
void prep1(const float* __restrict__ enc, const float* __restrict__ lq,
           const float* __restrict__ lwt, const float* __restrict__ ipw,
           const float* __restrict__ ow,
           u16* __restrict__ enc_b, float* __restrict__ pbuf)
{
    __shared__ u16 As[64 * 32];    // 4 KB
    __shared__ u16 Bs[128 * 32];   // 8 KB

    const int b = blockIdx.x, tid = threadIdx.x;

    if (b >= PB_TILE) {
        const long i8 = (long)(b - PB_TILE) * 2048 + (long)tid * 8;
        *reinterpret_cast<short8*>(enc_b + i8) = cvt8(enc + i8);
        return;
    }

    const int mat = b / 48, r2 = b % 48, kc = r2 / 6, jt = r2 % 6;
    const long n0 = (long)jt * 128;
    const bool isM2 = (mat == 1);
    const int lane = tid & 63, w = tid >> 6;
    const int rr = lane & 15, g = lane >> 4;

    f32x4 acc[4][2];
    #pragma unroll
    for (int m = 0; m < 4; ++m)
        #pragma unroll
        for (int n = 0; n < 2; ++n)
            #pragma unroll
            for (int j = 0; j < 4; ++j) acc[m][n][j] = 0.f;

    const float* Asrc = isM2 ? lwt : lq;

    #pragma unroll
    for (int ki = 0; ki < 3; ++ki) {
        const int k0 = kc * 96 + ki * 32;
        {
            const int row = tid >> 2, sp = tid & 3;
            short8 o;
            #pragma unroll
            for (int i = 0; i < 8; ++i) o[i] = 0;
            if (row < NL_) o = cvt8(Asrc + (long)row * H_ + k0 + sp * 8);
            const int ss = sp ^ ((row >> 1) & 3);
            *reinterpret_cast<short8*>(As + row * 32 + ss * 8) = o;
        }
        if (!isM2) {
            #pragma unroll
            for (int it = 0; it < 2; ++it) {
                const int gid = it * 256 + tid;
                const int row = gid >> 2, sp = gid & 3;
                const short8 o = cvt8(ipw + (n0 + row) * H_ + k0 + sp * 8);
                const int ss = sp ^ ((row >> 1) & 3);
                *reinterpret_cast<short8*>(Bs + row * 32 + ss * 8) = o;
            }
        } else {
            #pragma unroll
            for (int it = 0; it < 4; ++it) {
                const int gid = it * 256 + tid;       // kq*128 + n
                const int n = gid & 127, kq = gid >> 7;
                short4v o4;
                #pragma unroll
                for (int i = 0; i < 4; ++i)
                    o4[i] = f2b(ow[(long)(k0 + kq * 4 + i) * H_ + n0 + n]);
                const int byte = n * 64 + (((kq >> 1) ^ ((n >> 1) & 3)) << 4) + (kq & 1) * 8;
                *reinterpret_cast<short4v*>((char*)Bs + byte) = o4;
            }
        }
        __syncthreads();

        short8 a[4], bb[2];
        #pragma unroll
        for (int m = 0; m < 4; ++m) {
            const int row = m * 16 + rr;
            a[m] = *reinterpret_cast<const short8*>(As + row * 32 + ((g ^ ((row >> 1) & 3)) * 8));
        }
        #pragma unroll
        for (int n = 0; n < 2; ++n) {
            const int nr = w * 32 + n * 16 + rr;
            bb[n] = *reinterpret_cast<const short8*>(Bs + nr * 32 + ((g ^ ((nr >> 1) & 3)) * 8));
        }
        #pragma unroll
        for (int m = 0; m < 4; ++m)
            #pragma unroll
            for (int n = 0; n < 2; ++n)
                acc[m][n] = __builtin_amdgcn_mfma_f32_16x16x32_bf16(a[m], bb[n], acc[m][n], 0, 0, 0);
        __syncthreads();
    }

    float* P = pbuf + (long)(mat * KC_ + kc) * 64 * H_;
    #pragma unroll
    for (int m = 0; m < 4; ++m)
        #pragma unroll
        for (int n = 0; n < 2; ++n) {
            const long col = n0 + w * 32 + n * 16 + rr;
            #pragma unroll
            for (int j = 0; j < 4; ++j) {
                const int row = m * 16 + g * 4 + j;
                P[(long)row * H_ + col] = acc[m][n][j];
            }
        }
}

// ---------------------------------------------------------------------------
// prep2 (one launch):
//   blocks 0..143 : (mat, h, jt): qk/W2 = A_h @ wk_h/wv_h  MFMA, K=64 one-shot
//   blocks 144..193 : constL[l]
//   block 194 : zero pad rows 600..639 of qkL, W2L
// ---------------------------------------------------------------------------
__global__ __launch_bounds__(256)
void prep2(const float* __restrict__ pbuf, const float* __restrict__ ipw,
           const float* __restrict__ ipb, const float* __restrict__ lwt,
           const float* __restrict__ ob,
           u16* __restrict__ qkL, u16* __restrict__ W2L, float* __restrict__ constL)
{
    __shared__ u16 As2[64 * 64];    // 8 KB
    __shared__ u16 Bs2[128 * 64];   // 16 KB

    const int b = blockIdx.x, tid = threadIdx.x;

    if (b < 144) {
        const int mat = b / 72, r2 = b % 72, h = r2 / 6, jt = r2 % 6;
        const long n0 = (long)jt * 128;
        const int kb = H_ + mat * H_ + h * DH_;      // ipw row base (wk / wv)
        const int lane = tid & 63, w = tid >> 6;
        const int rr = lane & 15, g = lane >> 4;

        #pragma unroll
        for (int it = 0; it < 2; ++it) {
            const int gid = it * 256 + tid;          // row*8 + sp
            const int row = gid >> 3, sp = gid & 7;
            float a8[8];
            #pragma unroll
            for (int i = 0; i < 8; ++i) a8[i] = 0.f;
            #pragma unroll
            for (int kc = 0; kc < KC_; ++kc) {
                const float* p = pbuf + ((long)(mat * KC_ + kc) * 64 + row) * H_
                               + h * DH_ + sp * 8;
                const float4 v0 = *reinterpret_cast<const float4*>(p);
                const float4 v1 = *reinterpret_cast<const float4*>(p + 4);
                a8[0] += v0.x; a8[1] += v0.y; a8[2] += v0.z; a8[3] += v0.w;
                a8[4] += v1.x; a8[5] += v1.y; a8[6] += v1.z; a8[7] += v1.w;
            }
            short8 o;
            if (mat == 0) {
                #pragma unroll
                for (int i = 0; i < 8; ++i)
                    o[i] = f2b((row < NL_) ? 0.125f * (a8[i] + ipb[h * DH_ + sp * 8 + i]) : 0.f);
            } else {
                #pragma unroll
                for (int i = 0; i < 8; ++i) o[i] = f2b(a8[i]);
            }
            *reinterpret_cast<short8*>(As2 + row * 64 + ((sp ^ (row & 7)) * 8)) = o;
        }
        #pragma unroll
        for (int it = 0; it < 8; ++it) {
            const int gid = it * 256 + tid;          // kq*128 + n, kq 0..15
            const int n = gid & 127, kq = gid >> 7;
            short4v o4;
            #pragma unroll
            for (int i = 0; i < 4; ++i)
                o4[i] = f2b(ipw[(long)(kb + kq * 4 + i) * H_ + n0 + n]);
            const int byte = n * 128 + (((kq >> 1) ^ (n & 7)) << 4) + (kq & 1) * 8;
            *reinterpret_cast<short4v*>((char*)Bs2 + byte) = o4;
        }
        __syncthreads();

        f32x4 acc[4][2];
        #pragma unroll
        for (int m = 0; m < 4; ++m)
            #pragma unroll
            for (int n = 0; n < 2; ++n)
                #pragma unroll
                for (int j = 0; j < 4; ++j) acc[m][n][j] = 0.f;

        #pragma unroll
        for (int ks = 0; ks < 2; ++ks) {
            short8 a[4], bb[2];
            #pragma unroll
            for (int m = 0; m < 4; ++m) {
                const int row = m * 16 + rr, s = ks * 4 + g;
                a[m] = *reinterpret_cast<const short8*>(As2 + row * 64 + ((s ^ (row & 7)) * 8));
            }
            #pragma unroll
            for (int n = 0; n < 2; ++n) {
                const int nr = w * 32 + n * 16 + rr, s = ks * 4 + g;
                bb[n] = *reinterpret_cast<const short8*>(Bs2 + nr * 64 + ((s ^ (nr & 7)) * 8));
            }
            #pragma unroll
            for (int m = 0; m < 4; ++m)
                #pragma unroll
                for (int n = 0; n < 2; ++n)
                    acc[m][n] = __builtin_amdgcn_mfma_f32_16x16x32_bf16(a[m], bb[n], acc[m][n], 0, 0, 0);
        }

        u16* O = mat ? W2L : qkL;
        #pragma unroll
        for (int m = 0; m < 4; ++m)
            #pragma unroll
            for (int n = 0; n < 2; ++n) {
                const long col = n0 + w * 32 + n * 16 + rr;
                #pragma unroll
                for (int j = 0; j < 4; ++j) {
                    const int l = m * 16 + g * 4 + j;
                    if (l < NL_)
                        O[(long)(h * NL_ + l) * H_ + col] = f2b(acc[m][n][j]);
                }
            }
        return;
    }

    if (b < 194) {   // constL[l]
        const int l = b - 144;
        __shared__ float r4[4];
        const int lane = tid & 63, w = tid >> 6;
        float s = 0.f;
        #pragma unroll
        for (int r = 0; r < 3; ++r) {
            const int i = tid + 256 * r;
            float m2v = 0.f;
            #pragma unroll
            for (int kc = 0; kc < KC_; ++kc)
                m2v += pbuf[((long)(KC_ + kc) * 64 + l) * H_ + i];
            s += m2v * ipb[2 * H_ + i] + lwt[(long)l * H_ + i] * ob[i];
        }
        #pragma unroll
        for (int o2 = 1; o2 < 64; o2 <<= 1) s += __shfl_xor(s, o2);
        if (lane == 0) r4[w] = s;
        __syncthreads();
        if (tid == 0) constL[l] = r4[0] + r4[1] + r4[2] + r4[3];
        return;
    }

    {
        short8 z;
        #pragma unroll
        for (int i = 0; i < 8; ++i) z[i] = 0;
        for (int i = tid; i < 40 * H_ / 8; i += 256) {
            *reinterpret_cast<short8*>(qkL + (long)600 * H_ + i * 8) = z;
            *reinterpret_cast<short8*>(W2L + (long)600 * H_ + i * 8) = z;
        }
    }
}

// ---------------------------------------------------------------------------
// fused_gemm: block = (128 s-rows) x (64 lh-cols), BOTH logits (qk) and Z
// (W2), softmax partials in the epilogue. K-loop: 3-buffer rotation +
// counted vmcnt(4) + s_barrier, with the m201-style phase shape:
//   {vmcnt; barrier; ds_read cluster; stage issue; lgkmcnt(0); setprio(1);
//    pure-MFMA cluster; setprio(0)}
// ---------------------------------------------------------------------------
__global__ __launch_bounds__(256)
void fused_gemm(const u16* __restrict__ enc_b, const u16* __restrict__ qkL,
                const u16* __restrict__ W2L,
                float* __restrict__ pmg, float* __restrict__ ppg,
                float* __restrict__ pzg)
{
    const int flat = blockIdx.y * NT3_ + blockIdx.x;       // 0..639
    const int rem  = (flat & 7) * 80 + (flat >> 3);        // XCD-bijective
    const int mt   = rem / NT3_, ntb = rem % NT3_;
    const long m0 = (long)mt * 128, n0 = (long)ntb * 64;

    __shared__ u16 As[3][4096];      // 128 x 32
    __shared__ u16 Bqs[3][2048];     // 64 x 32
    __shared__ u16 Bzs[3][2048];
    __shared__ float redm[128], redsum[128], redz[128];

    const int tid = threadIdx.x, lane = tid & 63, w = tid >> 6;
    const int wr = w >> 1, wc = w & 1;
    const int sr0 = tid >> 2, sp = tid & 3;

    f32x4 accq[4][2], accz[4][2];
    #pragma unroll
    for (int m = 0; m < 4; ++m)
        #pragma unroll
        for (int n = 0; n < 2; ++n)
            #pragma unroll
            for (int j = 0; j < 4; ++j) { accq[m][n][j] = 0.f; accz[m][n][j] = 0.f; }

    auto stage = [&](int t, int buf) {
        const int k0 = t * 32;
        #pragma unroll
        for (int tt = 0; tt < 2; ++tt) {
            const int row = tt * 64 + sr0;
            const int ss  = sp ^ ((row >> 1) & 3);
            __builtin_amdgcn_global_load_lds(AS1(enc_b + (m0 + row) * H_ + k0 + ss * 8),
                                             AS3(As[buf] + (tt * 256 + tid) * 8), 16, 0, 0);
        }
        const int ss0 = sp ^ ((sr0 >> 1) & 3);
        __builtin_amdgcn_global_load_lds(AS1(qkL + (n0 + sr0) * H_ + k0 + ss0 * 8),
                                         AS3(Bqs[buf] + tid * 8), 16, 0, 0);
        __builtin_amdgcn_global_load_lds(AS1(W2L + (n0 + sr0) * H_ + k0 + ss0 * 8),
                                         AS3(Bzs[buf] + tid * 8), 16, 0, 0);
    };

    stage(0, 0);
    stage(1, 1);

    const int rr = lane & 15, g = lane >> 4;
    const int ro = (g ^ ((rr >> 1) & 3)) * 8;

    for (int t = 0; t < 24; ++t) {
        // tile t landed everywhere (own vmcnt + barrier publishes all waves)
        if (t < 23) asm volatile("s_waitcnt vmcnt(4)" ::: "memory");
        else        asm volatile("s_waitcnt vmcnt(0)" ::: "memory");
        __builtin_amdgcn_s_barrier();
        __builtin_amdgcn_sched_barrier(0);

        // --- phase A: ds_read cluster + next-tile stage issue ---
        const int cb = t % 3;
        short8 a[4], bq[2], bz[2];
        #pragma unroll
        for (int m = 0; m < 4; ++m)
            a[m] = *reinterpret_cast<const short8*>(As[cb] + (wr * 64 + m * 16 + rr) * 32 + ro);
        #pragma unroll
        for (int n = 0; n < 2; ++n) {
            bq[n] = *reinterpret_cast<const short8*>(Bqs[cb] + (wc * 32 + n * 16 + rr) * 32 + ro);
            bz[n] = *reinterpret_cast<const short8*>(Bzs[cb] + (wc * 32 + n * 16 + rr) * 32 + ro);
        }
        if (t + 2 < 24) stage(t + 2, (t + 2) % 3);   // safe: barrier above proves
                                                     // iter t-1 ds_reads consumed

        // --- phase B: pure MFMA cluster at raised priority ---
        asm volatile("s_waitcnt lgkmcnt(0)" ::: "memory");
        __builtin_amdgcn_sched_barrier(0);           // rule #18 fence
        __builtin_amdgcn_s_setprio(1);
        #pragma unroll
        for (int m = 0; m < 4; ++m)
            #pragma unroll
            for (int n = 0; n < 2; ++n) {
                accq[m][n] = __builtin_amdgcn_mfma_f32_16x16x32_bf16(a[m], bq[n], accq[m][n], 0, 0, 0);
                accz[m][n] = __builtin_amdgcn_mfma_f32_16x16x32_bf16(a[m], bz[n], accz[m][n], 0, 0, 0);
            }
        __builtin_amdgcn_s_setprio(0);
    }

    // ---- epilogue: softmax partials over this block's 128 rows ----
    #pragma unroll
    for (int n = 0; n < 2; ++n) {
        float m_ = -INFINITY;
        #pragma unroll
        for (int mm = 0; mm < 4; ++mm)
            #pragma unroll
            for (int j = 0; j < 4; ++j) m_ = fmaxf(m_, accq[mm][n][j]);
        m_ = fmaxf(m_, __shfl_xor(m_, 16));
        m_ = fmaxf(m_, __shfl_xor(m_, 32));
        if (g == 0) redm[wr * 64 + wc * 32 + n * 16 + rr] = m_;
    }
    __syncthreads();
    #pragma unroll
    for (int n = 0; n < 2; ++n) {
        const int col = wc * 32 + n * 16 + rr;
        const float gm = fmaxf(redm[col], redm[64 + col]);
        float s_ = 0.f, z_ = 0.f;
        #pragma unroll
        for (int mm = 0; mm < 4; ++mm)
            #pragma unroll
            for (int j = 0; j < 4; ++j) {
                const float e = __expf(accq[mm][n][j] - gm);
                s_ += e;
                z_ += e * accz[mm][n][j];
            }
        s_ += __shfl_xor(s_, 16); s_ += __shfl_xor(s_, 32);
        z_ += __shfl_xor(z_, 16); z_ += __shfl_xor(z_, 32);
        if (g == 0) { redsum[wr * 64 + col] = s_; redz[wr * 64 + col] = z_; }
    }
    __syncthreads();
    if (tid < 64) {
        const int col = tid;
        const long o = (long)mt * NLH_ + n0 + col;
        pmg[o] = fmaxf(redm[col], redm[64 + col]);
        ppg[o] = redsum[col] + redsum[64 + col];
        pzg[o] = redz[col] + redz[64 + col];
    }
}

// ---------------------------------------------------------------------------
// combine: block = label l, 64 threads. LDS-preload all partials, then 12
// threads run the serial flash-prefix from LDS; emit at every 4th m-tile.
// ---------------------------------------------------------------------------
__global__ __launch_bounds__(64)
void combine(const float* __restrict__ pmg, const float* __restrict__ ppg,
             const float* __restrict__ pzg, const float* __restrict__ constL,
             float* __restrict__ out)
{
    const int l = blockIdx.x, t = threadIdx.x;
    __shared__ float sm[64][12], sp_[64][12], sz[64][12];
    __shared__ float sc[16][12];

    #pragma unroll
    for (int h = 0; h < NH_; ++h) {
        const long o = (long)t * NLH_ + h * NL_ + l;
        sm[t][h]  = pmg[o];
        sp_[t][h] = ppg[o];
        sz[t][h]  = pzg[o];
    }
    __syncthreads();

    if (t < NH_) {
        float M = -INFINITY, S = 0.f, A = 0.f;
        for (int mt = 0; mt < MT_; ++mt) {
            const float mc = sm[mt][t], pc = sp_[mt][t], zc = sz[mt][t];
            const float Mn = fmaxf(M, mc);
            const float ea = __expf(M - Mn), eb = __expf(mc - Mn);
            S = S * ea + pc * eb;
            A = A * ea + zc * eb;
            M = Mn;
            if ((mt & 3) == 3) sc[mt >> 2][t] = A / S;
        }
    }
    __syncthreads();
    if (t < NC_) {
        float s = constL[l];
        #pragma unroll
        for (int h = 0; h < NH_; ++h) s += sc[t][h];
        out[(long)t * NL_ + l] = s;
    }
}

// ---------------------------------------------------------------------------
extern "C" void kernel_launch(void* const* d_in, const int* in_sizes, int n_in,
                              void* d_out, int out_size, void* d_ws, size_t ws_size,
                              hipStream_t stream) {
    const float* enc = (const float*)d_in[0];
    const float* lq  = (const float*)d_in[1];
    const float* lwt = (const float*)d_in[2];   // flat == lw (50, 768)
    const float* ipw = (const float*)d_in[3];
    const float* ipb = (const float*)d_in[4];
    const float* ow  = (const float*)d_in[5];
    const float* ob  = (const float*)d_in[6];
    float* out = (float*)d_out;

    // workspace
    float* wsf    = (float*)d_ws;
    float* pbuf   = wsf;                          // 2*8*64*768 = 786432
    float* constL = pbuf + (long)2 * KC_ * 64 * H_;  // 64
    float* pmg    = constL + 64;                  // 64*640
    float* ppg    = pmg + (long)MT_ * NLH_;
    float* pzg    = ppg + (long)MT_ * NLH_;
    u16* enc_b = (u16*)(pzg + (long)MT_ * NLH_);  // 8192*768
    u16* qkL   = enc_b + (long)S_ * H_;           // 640*768
    u16* W2L   = qkL + (long)NLH_ * H_;           // 640*768

    prep1<<<dim3(PB_TILE + 3072), 256, 0, stream>>>(
        enc, lq, lwt, ipw, ow, enc_b, pbuf);

    prep2<<<dim3(195), 256, 0, stream>>>(pbuf, ipw, ipb, lwt, ob,
                                         qkL, W2L, constL);

    fused_gemm<<<dim3(NT3_, MT_), 256, 0, stream>>>(enc_b, qkL, W2L, pmg, ppg, pzg);

    combine<<<dim3(NL_), 64, 0, stream>>>(pmg, ppg, pzg, constL, out);
}